// Round 6
// baseline (267.166 us; speedup 1.0000x reference)
//
#include <hip/hip_runtime.h>
#include <hip/hip_bf16.h>

// WaveNet dilated conv stack, MI355X gfx950. Round 6:
//  - 512-thread blocks (8 waves): wave (mw, nh) = (m-pair, n-half).
//    Halves each wave's serial chain, 16 waves/CU (was 8-12).
//  - accumulator chunking keeps VGPR <= 128 for __launch_bounds__(512,4)
//  - B-fragment read once, feeds both tanh & sigmoid MFMAs
//  - head: full-width as_ (2 syncs/layer); tail: separate as_ (2 syncs total)

#define CH 64
#define TLEN 16384
#define NB 8
#define BN 128
#define NLAYER 10

#define WP   192   // head window columns (col p <-> time t0-64+p)
#define PSTR 194   // head plane row stride: 194*16B % 128 = 32 -> bank spread
#define ASTR 194   // head as_ row stride (full width)

typedef __attribute__((ext_vector_type(4))) float f32x4;
typedef __attribute__((ext_vector_type(8))) short s16x8;
typedef __attribute__((ext_vector_type(4))) unsigned short u16x4;

__device__ __forceinline__ unsigned short f2bf(float f) {
    union { float f; unsigned u; } v; v.f = f;
    unsigned r = v.u + 0x7fffu + ((v.u >> 16) & 1u);  // RNE
    return (unsigned short)(r >> 16);
}
__device__ __forceinline__ float bf2f(unsigned short u) {
    union { unsigned u; float f; } v; v.u = ((unsigned)u) << 16;
    return v.f;
}
__device__ __forceinline__ void gload_lds16(const void* g, void* l) {
    __builtin_amdgcn_global_load_lds(
        (const __attribute__((address_space(1))) unsigned int*)g,
        (__attribute__((address_space(3))) unsigned int*)l, 16, 0, 0);
}

#define NCONV (NLAYER * 4 * 2 * 6 * 64 * 8)   // 245760 bf16: 10x 128x192 A-frags
#define NOUT  (NLAYER * 4 * 2 * 64 * 8)       // 40960  bf16: 10x 64x64 A-frags

__global__ void pack_weights(const float* __restrict__ wconv,
                             const float* __restrict__ wout,
                             unsigned short* __restrict__ wcpk,
                             unsigned short* __restrict__ wopk)
{
    int idx = blockIdx.x * 256 + threadIdx.x;
    if (idx < NCONV) {
        int j = idx & 7, t = idx >> 3;
        int lane = t & 63; t >>= 6;
        int ks = t % 6;   t /= 6;
        int m  = t & 1;   t >>= 1;
        int wv = t & 3;   int l = t >> 2;
        int o  = (m * 4 + wv) * 16 + (lane & 15);
        int ck = ks * 32 + (lane >> 4) * 8 + j;
        int kk = ck >> 6, c = ck & 63;
        wcpk[idx] = f2bf(wconv[(((size_t)l * 128 + o) * CH + c) * 3 + (2 - kk)]);
    } else if (idx < NCONV + NOUT) {
        int id = idx - NCONV;
        int j = id & 7, t = id >> 3;
        int lane = t & 63; t >>= 6;
        int ks = t & 1;    t >>= 1;
        int wv = t & 3;    int l = t >> 2;
        int o  = wv * 16 + (lane & 15);
        int c  = ks * 32 + (lane >> 4) * 8 + j;
        wopk[id] = f2bf(wout[((size_t)l * CH + o) * CH + c]);
    }
}

// ---------------- fused head: layers 0..4 (d = 1,2,4,8,16) ----------------
__global__ __launch_bounds__(512, 4)
void wavenet_head(const float* __restrict__ x, unsigned short* __restrict__ xplane,
                  float* __restrict__ out,
                  const unsigned short* __restrict__ wcpk,
                  const unsigned short* __restrict__ wopk,
                  const float* __restrict__ bconv, const float* __restrict__ bout)
{
    __shared__ __align__(16) unsigned short pl[2][8 * PSTR * 8];   // 2 x 24832 B
    __shared__ __align__(16) unsigned short as_[8 * ASTR * 8];     // 24832 B

    const int tid  = threadIdx.x;
    const int lane = tid & 63;
    const int wv8  = tid >> 6;      // 0..7
    const int mw   = wv8 & 3;       // m-pair (output rows mw*16.., 64+mw*16..)
    const int nh   = wv8 >> 2;      // n-half: tiles nh*6 .. nh*6+5
    const int hrow = lane & 15;
    const int kgrp = lane >> 4;
    const int b  = blockIdx.y;
    const int t0 = blockIdx.x * BN;
    const size_t xbase  = (size_t)b * CH * TLEN;
    const size_t planeF = (size_t)NB * CH * TLEN;

    // ---- stage input window: 1536 point-tasks over 512 threads ----
    #pragma unroll
    for (int it = 0; it < 3; ++it) {
        const int q  = it * 512 + tid;
        const int c8 = q / WP, p = q % WP;
        const int tt = t0 - 64 + p;
        s16x8 pk = {0, 0, 0, 0, 0, 0, 0, 0};
        if (tt >= 0) {
            const float* pp = x + xbase + (size_t)(c8 * 8) * TLEN + tt;
            #pragma unroll
            for (int j = 0; j < 8; ++j) pk[j] = (short)f2bf(pp[(size_t)j * TLEN]);
        }
        *reinterpret_cast<s16x8*>(&pl[0][(size_t)(c8 * PSTR + p) * 8]) = pk;
    }
    __syncthreads();

    int cur = 0;
    for (int l = 0; l < 5; ++l) {
        const int dil = 1 << l;
        unsigned short* plc = pl[cur];
        unsigned short* pln = pl[cur ^ 1];

        // conv weights: both m-rows of this wave's pair (48 VGPR)
        s16x8 w0[6], w1[6];
        {
            const unsigned short* basew = wcpk + ((size_t)(l * 4 + mw) * 768 + lane) * 8;
            #pragma unroll
            for (int ks = 0; ks < 6; ++ks) {
                w0[ks] = *reinterpret_cast<const s16x8*>(basew + (size_t)ks * 512);
                w1[ks] = *reinterpret_cast<const s16x8*>(basew + (size_t)(6 + ks) * 512);
            }
        }
        const float* Bc = bconv + (size_t)l * 128;
        float bt[4], bs[4];
        #pragma unroll
        for (int r = 0; r < 4; ++r) {
            bt[r] = Bc[mw * 16 + kgrp * 4 + r];
            bs[r] = Bc[64 + mw * 16 + kgrp * 4 + r];
        }
        float* skipl = out + (size_t)(1 + l) * planeF + xbase;

        // ---- conv + activation, 2 chunks of 3 n-tiles (acc dies per chunk) ----
        #pragma unroll 1
        for (int hf = 0; hf < 2; ++hf) {
            f32x4 accT[3], accS[3];
            #pragma unroll
            for (int i3 = 0; i3 < 3; ++i3) {
                accT[i3] = (f32x4){0.f, 0.f, 0.f, 0.f};
                accS[i3] = (f32x4){0.f, 0.f, 0.f, 0.f};
            }
            #pragma unroll
            for (int i3 = 0; i3 < 3; ++i3) {
                const int nt = nh * 6 + hf * 3 + i3;
                const int p  = nt * 16 + hrow;
                #pragma unroll
                for (int ks = 0; ks < 6; ++ks) {
                    const int kb = ks * 4 + kgrp;
                    const int kk = kb >> 3, c8i = kb & 7;
                    int q = p - kk * dil;
                    if (q < 0) q = 0;   // garbage halo cols only; never consumed
                    const s16x8 bf = *reinterpret_cast<const s16x8*>(
                        &plc[(size_t)(c8i * PSTR + q) * 8]);
                    accT[i3] = __builtin_amdgcn_mfma_f32_16x16x32_bf16(w0[ks], bf, accT[i3], 0, 0, 0);
                    accS[i3] = __builtin_amdgcn_mfma_f32_16x16x32_bf16(w1[ks], bf, accS[i3], 0, 0, 0);
                }
            }
            // activation for this chunk
            #pragma unroll
            for (int i3 = 0; i3 < 3; ++i3) {
                const int nt = nh * 6 + hf * 3 + i3;
                const int p  = nt * 16 + hrow;
                #pragma unroll
                for (int r = 0; r < 4; ++r) {
                    const float yt = accT[i3][r] + bt[r];
                    const float ys = accS[i3][r] + bs[r];
                    const float th = 2.f * __builtin_amdgcn_rcpf(1.f + __expf(-2.f * yt)) - 1.f;
                    const float sg = __builtin_amdgcn_rcpf(1.f + __expf(-ys));
                    const float av = th * sg;
                    const int c = mw * 16 + kgrp * 4 + r;
                    if (nt >= 4) skipl[(size_t)c * TLEN + t0 + p - 64] = av;
                    as_[(size_t)((c >> 3) * ASTR + p) * 8 + (c & 7)] = f2bf(av);
                }
            }
        }
        __syncthreads();

        // ---- 1x1 over this wave's 6 tiles ----
        s16x8 wa2[2];
        {
            const unsigned short* b2 = wopk + ((size_t)(l * 4 + mw) * 128 + lane) * 8;
            wa2[0] = *reinterpret_cast<const s16x8*>(b2);
            wa2[1] = *reinterpret_cast<const s16x8*>(b2 + 512);
        }
        const float* Bo = bout + (size_t)l * CH;
        float bo[4];
        #pragma unroll
        for (int r = 0; r < 4; ++r) bo[r] = Bo[mw * 16 + kgrp * 4 + r];
        const int o0 = mw * 16 + kgrp * 4;

        #pragma unroll
        for (int i = 0; i < 6; ++i) {
            const int nt = nh * 6 + i;
            const int p  = nt * 16 + hrow;
            f32x4 a2 = (f32x4){0.f, 0.f, 0.f, 0.f};
            #pragma unroll
            for (int ks2 = 0; ks2 < 2; ++ks2) {
                const s16x8 bf = *reinterpret_cast<const s16x8*>(
                    &as_[(size_t)((ks2 * 4 + kgrp) * ASTR + p) * 8]);
                a2 = __builtin_amdgcn_mfma_f32_16x16x32_bf16(wa2[ks2], bf, a2, 0, 0, 0);
            }
            const int tt = t0 - 64 + p;
            const u16x4 rv = *reinterpret_cast<const u16x4*>(
                &plc[(size_t)((o0 >> 3) * PSTR + p) * 8 + (o0 & 7)]);
            if (l == 4) {
                if (nt >= 4) {
                    u16x4 ov;
                    #pragma unroll
                    for (int r = 0; r < 4; ++r) ov[r] = f2bf(a2[r] + bo[r] + bf2f(rv[r]));
                    *reinterpret_cast<u16x4*>(&xplane[xbase + (size_t)tt * CH + o0]) = ov;
                }
            } else {
                u16x4 ov;
                #pragma unroll
                for (int r = 0; r < 4; ++r)
                    ov[r] = (tt >= 0) ? f2bf(a2[r] + bo[r] + bf2f(rv[r])) : (unsigned short)0;
                *reinterpret_cast<u16x4*>(&pln[(size_t)((o0 >> 3) * PSTR + p) * 8 + (o0 & 7)]) = ov;
            }
        }
        __syncthreads();

        cur ^= 1;
    }
}

// ------------- tail layers 5..9 -------------
// SM: 1 = bf16 [T][C] single window (dil<=64), 2 = bf16 [T][C] triple-tap
template<int SM, bool LAST>
__global__ __launch_bounds__(512, 4)
void wavenet_layer(const void* __restrict__ xin_, void* __restrict__ xout_,
                   float* __restrict__ skip,
                   const unsigned short* __restrict__ wcpk,
                   const unsigned short* __restrict__ wopk,
                   const float* __restrict__ bconv, const float* __restrict__ bout,
                   int layer, int dil)
{
    extern __shared__ __align__(16) unsigned short xs[];
    __shared__ __align__(16) unsigned short as_[8 * BN * 8];   // 16 KB

    const int tid  = threadIdx.x;
    const int lane = tid & 63;
    const int wv8  = tid >> 6;
    const int mw   = wv8 & 3;
    const int nh   = wv8 >> 2;      // n-half: tiles nh*4 .. nh*4+3
    const int hrow = lane & 15;
    const int kgrp = lane >> 4;
    const int b  = blockIdx.y;
    const int t0 = blockIdx.x * BN;
    const int NW = BN + 2 * dil;
    const size_t xbase = (size_t)b * CH * TLEN;

    // ---- stage X into LDS (8 waves) ----
    if (SM == 1) {
        const unsigned short* xin = (const unsigned short*)xin_;
        const int cnt_n = (NW + 63) >> 6;
        if (t0 >= 2 * dil) {
            for (int ch = wv8; ch < 8 * cnt_n; ch += 8) {
                const int c8 = ch / cnt_n;
                const int n0 = (ch % cnt_n) * 64;
                const int rem = NW - n0;
                const unsigned short* src =
                    xin + xbase + (size_t)(t0 - 2 * dil + n0 + lane) * CH + c8 * 8;
                unsigned short* dst = &xs[(size_t)(c8 * NW + n0) * 8];
                if (rem >= 64) gload_lds16(src, dst);
                else if (lane < rem) gload_lds16(src, dst);
            }
        } else {
            for (int ch = wv8; ch < 8 * cnt_n; ch += 8) {
                const int c8 = ch / cnt_n;
                const int n0 = (ch % cnt_n) * 64;
                if (n0 + lane < NW) {
                    const int tg = t0 - 2 * dil + n0 + lane;
                    s16x8 pk = {0, 0, 0, 0, 0, 0, 0, 0};
                    if (tg >= 0)
                        pk = *reinterpret_cast<const s16x8*>(xin + xbase + (size_t)tg * CH + c8 * 8);
                    *reinterpret_cast<s16x8*>(&xs[(size_t)(c8 * NW + n0 + lane) * 8]) = pk;
                }
            }
        }
    } else {
        const unsigned short* xin = (const unsigned short*)xin_;
        if (t0 >= 2 * dil) {
            for (int ch = wv8; ch < 48; ch += 8) {
                const int kk = ch >> 4, c8 = (ch >> 1) & 7, n0 = (ch & 1) * 64;
                const unsigned short* src =
                    xin + xbase + (size_t)(t0 + n0 + lane - kk * dil) * CH + c8 * 8;
                unsigned short* dst = &xs[(size_t)((kk * 8 + c8) * BN + n0) * 8];
                gload_lds16(src, dst);
            }
        } else {
            for (int ch = wv8; ch < 48; ch += 8) {
                const int kk = ch >> 4, c8 = (ch >> 1) & 7, n0 = (ch & 1) * 64;
                const int tg = t0 + n0 + lane - kk * dil;
                s16x8 pk = {0, 0, 0, 0, 0, 0, 0, 0};
                if (tg >= 0)
                    pk = *reinterpret_cast<const s16x8*>(xin + xbase + (size_t)tg * CH + c8 * 8);
                *reinterpret_cast<s16x8*>(&xs[(size_t)((kk * 8 + c8) * BN + n0 + lane) * 8]) = pk;
            }
        }
    }

    // conv weights (both m-rows, 48 VGPR)
    s16x8 w0[6], w1[6];
    {
        const unsigned short* basew = wcpk + ((size_t)(layer * 4 + mw) * 768 + lane) * 8;
        #pragma unroll
        for (int ks = 0; ks < 6; ++ks) {
            w0[ks] = *reinterpret_cast<const s16x8*>(basew + (size_t)ks * 512);
            w1[ks] = *reinterpret_cast<const s16x8*>(basew + (size_t)(6 + ks) * 512);
        }
    }
    const float* Bc = bconv + (size_t)layer * 128;
    float bt[4], bs[4];
    #pragma unroll
    for (int r = 0; r < 4; ++r) {
        bt[r] = Bc[mw * 16 + kgrp * 4 + r];
        bs[r] = Bc[64 + mw * 16 + kgrp * 4 + r];
    }

    __syncthreads();

    // ---- conv + activation, 2 chunks of 2 n-tiles ----
    #pragma unroll 1
    for (int hf = 0; hf < 2; ++hf) {
        f32x4 accT[2], accS[2];
        #pragma unroll
        for (int i2 = 0; i2 < 2; ++i2) {
            accT[i2] = (f32x4){0.f, 0.f, 0.f, 0.f};
            accS[i2] = (f32x4){0.f, 0.f, 0.f, 0.f};
        }
        #pragma unroll
        for (int i2 = 0; i2 < 2; ++i2) {
            const int nt = nh * 4 + hf * 2 + i2;
            #pragma unroll
            for (int ks = 0; ks < 6; ++ks) {
                const int kb = ks * 4 + kgrp;
                const unsigned short* bp;
                if (SM == 2) {
                    bp = &xs[(size_t)(kb * BN + nt * 16 + hrow) * 8];
                } else {
                    const int kk = kb >> 3, c8i = kb & 7;
                    bp = &xs[(size_t)(c8i * NW + nt * 16 + hrow + (2 - kk) * dil) * 8];
                }
                const s16x8 bf = *reinterpret_cast<const s16x8*>(bp);
                accT[i2] = __builtin_amdgcn_mfma_f32_16x16x32_bf16(w0[ks], bf, accT[i2], 0, 0, 0);
                accS[i2] = __builtin_amdgcn_mfma_f32_16x16x32_bf16(w1[ks], bf, accS[i2], 0, 0, 0);
            }
        }
        #pragma unroll
        for (int i2 = 0; i2 < 2; ++i2) {
            const int nt = nh * 4 + hf * 2 + i2;
            const int n  = nt * 16 + hrow;
            #pragma unroll
            for (int r = 0; r < 4; ++r) {
                const float yt = accT[i2][r] + bt[r];
                const float ys = accS[i2][r] + bs[r];
                const float th = 2.f * __builtin_amdgcn_rcpf(1.f + __expf(-2.f * yt)) - 1.f;
                const float sg = __builtin_amdgcn_rcpf(1.f + __expf(-ys));
                const float av = th * sg;
                const int c = mw * 16 + kgrp * 4 + r;
                skip[xbase + (size_t)c * TLEN + t0 + n] = av;
                if (LAST) {
                    const float res = bf2f(xs[(size_t)((c >> 3) * BN + n) * 8 + (c & 7)]);
                    ((float*)xout_)[xbase + (size_t)c * TLEN + t0 + n] = av + res;
                } else {
                    as_[(size_t)((c >> 3) * BN + n) * 8 + (c & 7)] = f2bf(av);
                }
            }
        }
    }

    if (LAST) return;

    __syncthreads();

    // ---- 1x1: out = Wout * a + bias + residual, stored bf16 [T][C] ----
    s16x8 wa2[2];
    {
        const unsigned short* b2 = wopk + ((size_t)(layer * 4 + mw) * 128 + lane) * 8;
        wa2[0] = *reinterpret_cast<const s16x8*>(b2);
        wa2[1] = *reinterpret_cast<const s16x8*>(b2 + 512);
    }
    const float* Bo = bout + (size_t)layer * CH;
    float bo[4];
    #pragma unroll
    for (int r = 0; r < 4; ++r) bo[r] = Bo[mw * 16 + kgrp * 4 + r];

    const int o0 = mw * 16 + kgrp * 4;
    unsigned short* xout = (unsigned short*)xout_;

    #pragma unroll
    for (int i = 0; i < 4; ++i) {
        const int nt = nh * 4 + i;
        const int n  = nt * 16 + hrow;
        f32x4 acc = (f32x4){0.f, 0.f, 0.f, 0.f};
        #pragma unroll
        for (int ks = 0; ks < 2; ++ks) {
            const s16x8 bf = *reinterpret_cast<const s16x8*>(
                &as_[(size_t)((ks * 4 + kgrp) * BN + n) * 8]);
            acc = __builtin_amdgcn_mfma_f32_16x16x32_bf16(wa2[ks], bf, acc, 0, 0, 0);
        }
        const u16x4 rv = *reinterpret_cast<const u16x4*>(
            (const unsigned short*)xin_ + xbase + (size_t)(t0 + n) * CH + o0);
        u16x4 ov;
        #pragma unroll
        for (int r = 0; r < 4; ++r) ov[r] = f2bf(acc[r] + bo[r] + bf2f(rv[r]));
        *reinterpret_cast<u16x4*>(&xout[xbase + (size_t)(t0 + n) * CH + o0]) = ov;
    }
}

extern "C" void kernel_launch(void* const* d_in, const int* in_sizes, int n_in,
                              void* d_out, int out_size, void* d_ws, size_t ws_size,
                              hipStream_t stream)
{
    const float* x  = (const float*)d_in[0];
    const float* wc = (const float*)d_in[1];
    const float* bc = (const float*)d_in[2];
    const float* wo = (const float*)d_in[3];
    const float* bo = (const float*)d_in[4];
    float* out = (float*)d_out;
    const size_t planeF  = (size_t)NB * CH * TLEN;
    const size_t planeBy = planeF * sizeof(unsigned short);

    unsigned short* P0 = (unsigned short*)d_ws;
    unsigned short* P1 = (unsigned short*)((char*)d_ws + planeBy);
    unsigned short* wcpk = (unsigned short*)((char*)d_ws + 2 * planeBy);
    unsigned short* wopk = wcpk + NCONV;

    pack_weights<<<(NCONV + NOUT) / 256, 256, 0, stream>>>(wc, wo, wcpk, wopk);

    dim3 grid(TLEN / BN, NB), block(512);

    // layers 0-4 fused: fp32 x -> skips 1..5 + bf16 plane P0
    wavenet_head<<<grid, block, 0, stream>>>(x, P0, out, wcpk, wopk, bc, bo);

    // layer 5 (d=32), 6 (d=64): single-window
    wavenet_layer<1, false><<<grid, block, (size_t)(BN + 64) * 128, stream>>>(
        P0, P1, out + 6 * planeF, wcpk, wopk, bc, bo, 5, 32);
    wavenet_layer<1, false><<<grid, block, (size_t)(BN + 128) * 128, stream>>>(
        P1, P0, out + 7 * planeF, wcpk, wopk, bc, bo, 6, 64);
    // layer 7 (d=128), 8 (d=256): triple-tap
    wavenet_layer<2, false><<<grid, block, 24 * BN * 8 * 2, stream>>>(
        P0, P1, out + 8 * planeF, wcpk, wopk, bc, bo, 7, 128);
    wavenet_layer<2, false><<<grid, block, 24 * BN * 8 * 2, stream>>>(
        P1, P0, out + 9 * planeF, wcpk, wopk, bc, bo, 8, 256);
    // layer 9 (d=512): triple-tap, residual from LDS, fp32 out slot 0
    wavenet_layer<2, true><<<grid, block, 24 * BN * 8 * 2, stream>>>(
        P0, out, out + 10 * planeF, wcpk, wopk, bc, bo, 9, 512);
}